// Round 1
// baseline (1417.490 us; speedup 1.0000x reference)
//
#include <hip/hip_runtime.h>
#include <math.h>

// ---------------- problem constants ----------------
#define Bn 4
#define Tn 8
#define Hn 120
#define Wn 160
#define HWn (Hn * Wn)
#define NON_SEMn 4
#define CATn 16
#define MAP_CHn 20
#define FEAT_CHn 24
#define LOCAL_Mn 240
#define GLOBAL_Mn 960
#define M2n (LOCAL_Mn * LOCAL_Mn)

#define DEG2RADf ((float)0.017453292519943295)

// output layout (float element offsets into d_out)
#define OUT_FEATS 0                           // B*T*24*M2 = 44,236,800
#define OUT_LMAP  44236800                    // B*20*M2   =  4,608,000
#define OUT_GMAP  48844800                    // B*20*960² = 73,728,000
#define OUT_LP    122572800                   // B*T*3
#define OUT_GP    122572896                   // B*T*3
#define OUT_BNDS  122572992                   // B*T*4 (written as float)
#define OUT_ORGS  122573120                   // B*T*3

// workspace layout (float element offsets into d_ws)
#define WS_LPOSE   0                          // T*B*3 = 96
#define WS_ANYDONE 96                         // B (float 0/1)
#define WS_EXP     128                        // B*M2 = 230,400
#define WS_OBST    (WS_EXP + Bn * M2n)        // B*M2
#define WS_SEM     (WS_OBST + Bn * M2n)       // B*CAT*M2 = 3,686,400
#define WS_LMAP    (WS_SEM + Bn * CATn * M2n) // B*20*M2
#define WS_CROP    (WS_LMAP + Bn * MAP_CHn * M2n)
#define SCRATCH_FLOATS (Bn * M2n * 2 + Bn * CATn * M2n)

// ---------------- kernels ----------------

// Poses/bounds/origins evolve independently of the maps: compute all T steps
// up front, write pose outputs, stash per-step lpose + any_done flag in ws.
__global__ void pose_kernel(const float* __restrict__ pose_delta,
                            const int* __restrict__ done_flags,
                            const int* __restrict__ upd_flags,
                            const float* __restrict__ init_lpose,
                            const float* __restrict__ init_gpose,
                            const int* __restrict__ init_bounds,
                            const float* __restrict__ init_origins,
                            float* __restrict__ ws_lpose,
                            float* __restrict__ ws_anydone,
                            float* __restrict__ out_lp,
                            float* __restrict__ out_gp,
                            float* __restrict__ out_bnds,
                            float* __restrict__ out_orgs) {
#pragma clang fp contract(off)
    int b = threadIdx.x;
    if (b >= Bn) return;
    float lx = init_lpose[b * 3 + 0], ly = init_lpose[b * 3 + 1], lz = init_lpose[b * 3 + 2];
    float gx = init_gpose[b * 3 + 0], gy = init_gpose[b * 3 + 1], gz = init_gpose[b * 3 + 2];
    int b0 = init_bounds[b * 4 + 0], b1 = init_bounds[b * 4 + 1];
    int b2i = init_bounds[b * 4 + 2], b3 = init_bounds[b * 4 + 3];
    float ox = init_origins[b * 3 + 0], oy = init_origins[b * 3 + 1], oz = init_origins[b * 3 + 2];
    float anyd = 0.0f;
    for (int t = 0; t < Tn; t++) {
        int done = done_flags[b * Tn + t];
        int upd  = upd_flags[b * Tn + t];
        if (done) {
            lx = 600.0f; ly = 600.0f; lz = 0.0f;
            gx = 2400.0f; gy = 2400.0f; gz = 0.0f;
            b0 = 360; b1 = 600; b2i = 360; b3 = 600;
            ox = 1800.0f; oy = 1800.0f; oz = 0.0f;
            anyd = 1.0f;
        }
        float th = lz * DEG2RADf;
        float c = cosf(th), s = sinf(th);
        float d0 = pose_delta[(b * Tn + t) * 3 + 0];
        float d1 = pose_delta[(b * Tn + t) * 3 + 1];
        float d2 = pose_delta[(b * Tn + t) * 3 + 2];
        lx = lx + (d0 * c - d1 * s);
        ly = ly + (d0 * s + d1 * c);
        lz = lz + d2;
        if (upd) { gx = lx + ox; gy = ly + oy; gz = lz + oz; }
        ws_lpose[(t * Bn + b) * 3 + 0] = lx;
        ws_lpose[(t * Bn + b) * 3 + 1] = ly;
        ws_lpose[(t * Bn + b) * 3 + 2] = lz;
        out_lp[(b * Tn + t) * 3 + 0] = lx;
        out_lp[(b * Tn + t) * 3 + 1] = ly;
        out_lp[(b * Tn + t) * 3 + 2] = lz;
        out_gp[(b * Tn + t) * 3 + 0] = gx;
        out_gp[(b * Tn + t) * 3 + 1] = gy;
        out_gp[(b * Tn + t) * 3 + 2] = gz;
        out_bnds[(b * Tn + t) * 4 + 0] = (float)b0;
        out_bnds[(b * Tn + t) * 4 + 1] = (float)b1;
        out_bnds[(b * Tn + t) * 4 + 2] = (float)b2i;
        out_bnds[(b * Tn + t) * 4 + 3] = (float)b3;
        out_orgs[(b * Tn + t) * 3 + 0] = ox;
        out_orgs[(b * Tn + t) * 3 + 1] = oy;
        out_orgs[(b * Tn + t) * 3 + 2] = oz;
    }
    ws_anydone[b] = anyd;
}

// Copy init_local_map -> lmap state; init_global_map fixed crop -> crop state.
__global__ void init_state_kernel(const float* __restrict__ init_lmap,
                                  const float* __restrict__ init_gmap,
                                  const int* __restrict__ init_bounds,
                                  float* __restrict__ lmap_st,
                                  float* __restrict__ crop_st) {
    int idx = blockIdx.x * blockDim.x + threadIdx.x;
    if (idx >= Bn * MAP_CHn * M2n) return;
    lmap_st[idx] = init_lmap[idx];
    int j = idx % M2n;
    int bc = idx / M2n;          // b*MAP_CH + ch
    int b = bc / MAP_CHn;
    int y = j / LOCAL_Mn, x = j % LOCAL_Mn;
    int y1 = init_bounds[b * 4 + 0];
    int x1 = init_bounds[b * 4 + 2];
    crop_st[idx] = init_gmap[((size_t)bc * GLOBAL_Mn + (y1 + y)) * GLOBAL_Mn + (x1 + x)];
}

// Depth unprojection + cam transform + world->grid; atomic splat into scratch grids.
__global__ void project_kernel(const float* __restrict__ obs,
                               const float* __restrict__ cam,
                               const float* __restrict__ ws_lpose,
                               float* __restrict__ g_exp,
                               float* __restrict__ g_obst,
                               float* __restrict__ g_sem,
                               int t, float fx) {
#pragma clang fp contract(off)
    int idx = blockIdx.x * blockDim.x + threadIdx.x;
    if (idx >= Bn * HWn) return;
    int b = idx / HWn, p = idx % HWn;
    int h = p / Wn, w = p % Wn;
    const float* ob = obs + (size_t)((b * Tn + t) * MAP_CHn) * HWn;
    float depth = ob[3 * HWn + p] * 400.0f + 50.0f;
    float u = (float)w - 80.0f;   // CX = W/2
    float v = 60.0f - (float)h;   // CY = H/2
    float px = u * depth / fx;
    float py = v * depth / fx;    // FY == FX
    float pz = depth;
    const float* Tm = cam + (size_t)(b * Tn + t) * 16;
    float X = ((Tm[0] * px + Tm[1] * py) + Tm[2] * pz) + Tm[3];
    float Y = ((Tm[4] * px + Tm[5] * py) + Tm[6] * pz) + Tm[7];
    float Z = ((Tm[8] * px + Tm[9] * py) + Tm[10] * pz) + Tm[11];
    float x_f = Z;
    float y_l = -X;
    float z_u = Y + 88.0f;        // CAM_H_CM
    float lx = ws_lpose[(t * Bn + b) * 3 + 0];
    float ly = ws_lpose[(t * Bn + b) * 3 + 1];
    float lz = ws_lpose[(t * Bn + b) * 3 + 2];
    float th2 = lz * DEG2RADf;
    float c2 = cosf(th2), s2 = sinf(th2);
    float wx = (lx + x_f * c2) - y_l * s2;
    float wy = (ly + x_f * s2) + y_l * c2;
    int ix = (int)floorf(wx / 5.0f);
    int iy = (int)floorf(wy / 5.0f);
    bool valid = (depth > 25.0f) && (depth < 500.0f) &&
                 (ix >= 0) && (ix < LOCAL_Mn) && (iy >= 0) && (iy < LOCAL_Mn);
    if (!valid) return;
    int flat = iy * LOCAL_Mn + ix;
    atomicAdd(&g_exp[b * M2n + flat], 1.0f);
    if (z_u > 25.0f && z_u < 150.0f) atomicAdd(&g_obst[b * M2n + flat], 1.0f);
#pragma unroll
    for (int c = 0; c < CATn; c++) {
        float sv = ob[(size_t)(NON_SEMn + c) * HWn + p];
        atomicAdd(&g_sem[(size_t)(b * CATn + c) * M2n + flat], sv);
    }
}

// Per-cell: build new lmap (20ch), fuse crop window, emit 24ch feats.
__global__ void update_kernel(const float* __restrict__ g_exp,
                              const float* __restrict__ g_obst,
                              const float* __restrict__ g_sem,
                              const int* __restrict__ done_flags,
                              const int* __restrict__ upd_flags,
                              const float* __restrict__ ws_lpose,
                              float* __restrict__ lmap_st,
                              float* __restrict__ crop_st,
                              float* __restrict__ out_feats,
                              float* __restrict__ out_lmap,
                              int t) {
#pragma clang fp contract(off)
    int idx = blockIdx.x * blockDim.x + threadIdx.x;
    if (idx >= Bn * M2n) return;
    int b = idx / M2n, j = idx % M2n;
    int y = j / LOCAL_Mn, x = j % LOCAL_Mn;
    int done = done_flags[b * Tn + t];
    int upd  = upd_flags[b * Tn + t];
    float lx = ws_lpose[(t * Bn + b) * 3 + 0];
    float ly = ws_lpose[(t * Bn + b) * 3 + 1];
    float dxg = (float)x - lx / 5.0f;
    float dyg = (float)y - ly / 5.0f;
    float d2 = dxg * dxg + dyg * dyg;
    float agent = (d2 <= 4.0f) ? 1.0f : 0.0f;
    float close = (d2 <= 9.0f) ? 1.0f : 0.0f;

    float nl[MAP_CHn];
    float expv  = g_exp[b * M2n + j];
    float obstv = g_obst[b * M2n + j];
    float p0 = done ? 0.0f : lmap_st[((size_t)(b * MAP_CHn + 0)) * M2n + j];
    float p1 = done ? 0.0f : lmap_st[((size_t)(b * MAP_CHn + 1)) * M2n + j];
    float p3 = done ? 0.0f : lmap_st[((size_t)(b * MAP_CHn + 3)) * M2n + j];
    nl[0] = fmaxf(p0, fminf(fmaxf(obstv, 0.0f), 1.0f));
    nl[1] = fmaxf(p1, fminf(fmaxf(expv, 0.0f), 1.0f));
    nl[2] = agent;
    nl[3] = fmaxf(p3, close);
#pragma unroll
    for (int c = 0; c < CATn; c++) {
        float pv = done ? 0.0f : lmap_st[((size_t)(b * MAP_CHn + NON_SEMn + c)) * M2n + j];
        float sv = g_sem[((size_t)(b * CATn + c)) * M2n + j];
        nl[NON_SEMn + c] = fmaxf(pv, fminf(fmaxf(sv, 0.0f), 1.0f));
    }

    float fused[MAP_CHn];
#pragma unroll
    for (int ch = 0; ch < MAP_CHn; ch++) {
        float cp = done ? 0.0f : crop_st[((size_t)(b * MAP_CHn + ch)) * M2n + j];
        fused[ch] = upd ? fmaxf(cp, nl[ch]) : cp;
    }

    // persist state
    if (t < Tn - 1) {
#pragma unroll
        for (int ch = 0; ch < MAP_CHn; ch++)
            lmap_st[((size_t)(b * MAP_CHn + ch)) * M2n + j] = nl[ch];
    } else {
        // last step: lmap state is the OUT1 output, skip the ws write
#pragma unroll
        for (int ch = 0; ch < MAP_CHn; ch++)
            out_lmap[((size_t)(b * MAP_CHn + ch)) * M2n + j] = nl[ch];
    }
#pragma unroll
    for (int ch = 0; ch < MAP_CHn; ch++)
        crop_st[((size_t)(b * MAP_CHn + ch)) * M2n + j] = fused[ch];

    // feats: [nl[0:4], fused[0:4], nl[4:20]]
    size_t fb = ((size_t)(b * Tn + t) * FEAT_CHn) * M2n + j;
#pragma unroll
    for (int ch = 0; ch < NON_SEMn; ch++) out_feats[fb + (size_t)ch * M2n] = nl[ch];
#pragma unroll
    for (int ch = 0; ch < NON_SEMn; ch++) out_feats[fb + (size_t)(NON_SEMn + ch) * M2n] = fused[ch];
#pragma unroll
    for (int c = 0; c < CATn; c++) out_feats[fb + (size_t)(2 * NON_SEMn + c) * M2n] = nl[NON_SEMn + c];
}

// Final global map: inside fixed crop window -> crop state; outside -> 0 if any
// done occurred (gmap was zeroed), else init_global_map.
__global__ void final_gmap_kernel(const float* __restrict__ init_gmap,
                                  const float* __restrict__ crop_st,
                                  const int* __restrict__ init_bounds,
                                  const float* __restrict__ anydone,
                                  float* __restrict__ out_gmap) {
    size_t idx = (size_t)blockIdx.x * blockDim.x + threadIdx.x;
    const size_t total = (size_t)Bn * MAP_CHn * GLOBAL_Mn * GLOBAL_Mn;
    if (idx >= total) return;
    int gx = (int)(idx % GLOBAL_Mn);
    size_t r = idx / GLOBAL_Mn;
    int gy = (int)(r % GLOBAL_Mn);
    size_t bc = r / GLOBAL_Mn;      // b*MAP_CH + ch
    int b = (int)(bc / MAP_CHn);
    int y1 = init_bounds[b * 4 + 0];
    int x1 = init_bounds[b * 4 + 2];
    float v;
    if (gy >= y1 && gy < y1 + LOCAL_Mn && gx >= x1 && gx < x1 + LOCAL_Mn) {
        v = crop_st[bc * M2n + (size_t)(gy - y1) * LOCAL_Mn + (gx - x1)];
    } else {
        v = (anydone[b] != 0.0f) ? 0.0f : init_gmap[idx];
    }
    out_gmap[idx] = v;
}

// ---------------- launch ----------------
extern "C" void kernel_launch(void* const* d_in, const int* in_sizes, int n_in,
                              void* d_out, int out_size, void* d_ws, size_t ws_size,
                              hipStream_t stream) {
    const float* obs        = (const float*)d_in[0];
    const float* pose_delta = (const float*)d_in[1];
    const int*   done_flags = (const int*)d_in[2];
    const int*   upd_flags  = (const int*)d_in[3];
    const float* cam_poses  = (const float*)d_in[4];
    const float* init_lmap  = (const float*)d_in[5];
    const float* init_gmap  = (const float*)d_in[6];
    const float* init_lpose = (const float*)d_in[7];
    const float* init_gpose = (const float*)d_in[8];
    const int*   init_bnds  = (const int*)d_in[9];
    const float* init_orgs  = (const float*)d_in[10];

    float* out = (float*)d_out;
    float* ws  = (float*)d_ws;

    float* ws_lpose = ws + WS_LPOSE;
    float* ws_anyd  = ws + WS_ANYDONE;
    float* g_exp    = ws + WS_EXP;
    float* g_obst   = ws + WS_OBST;
    float* g_sem    = ws + WS_SEM;
    float* lmap_st  = ws + WS_LMAP;
    float* crop_st  = ws + WS_CROP;

    // FX = W / (2*tan(deg2rad(HFOV)/2)), double math then f32 (matches numpy)
    float fx = (float)(160.0 / (2.0 * tan(79.0 * M_PI / 180.0 / 2.0)));

    pose_kernel<<<1, 64, 0, stream>>>(pose_delta, done_flags, upd_flags,
                                      init_lpose, init_gpose, init_bnds, init_orgs,
                                      ws_lpose, ws_anyd,
                                      out + OUT_LP, out + OUT_GP,
                                      out + OUT_BNDS, out + OUT_ORGS);

    init_state_kernel<<<(Bn * MAP_CHn * M2n + 255) / 256, 256, 0, stream>>>(
        init_lmap, init_gmap, init_bnds, lmap_st, crop_st);

    for (int t = 0; t < Tn; t++) {
        hipMemsetAsync(g_exp, 0, (size_t)SCRATCH_FLOATS * sizeof(float), stream);
        project_kernel<<<(Bn * HWn + 255) / 256, 256, 0, stream>>>(
            obs, cam_poses, ws_lpose, g_exp, g_obst, g_sem, t, fx);
        update_kernel<<<(Bn * M2n + 255) / 256, 256, 0, stream>>>(
            g_exp, g_obst, g_sem, done_flags, upd_flags, ws_lpose,
            lmap_st, crop_st, out + OUT_FEATS, out + OUT_LMAP, t);
    }

    const size_t gmap_total = (size_t)Bn * MAP_CHn * GLOBAL_Mn * GLOBAL_Mn;
    final_gmap_kernel<<<(int)((gmap_total + 255) / 256), 256, 0, stream>>>(
        init_gmap, crop_st, init_bnds, ws_anyd, out + OUT_GMAP);
}

// Round 2
// 1229.334 us; speedup vs baseline: 1.1531x; 1.1531x over previous
//
#include <hip/hip_runtime.h>
#include <math.h>

// ---------------- problem constants ----------------
#define Bn 4
#define Tn 8
#define Hn 120
#define Wn 160
#define HWn (Hn * Wn)
#define NON_SEMn 4
#define CATn 16
#define MAP_CHn 20
#define FEAT_CHn 24
#define LOCAL_Mn 240
#define GLOBAL_Mn 960
#define M2n (LOCAL_Mn * LOCAL_Mn)

#define DEG2RADf ((float)0.017453292519943295)

// output layout (float element offsets into d_out)
#define OUT_FEATS 0                           // B*T*24*M2 = 44,236,800
#define OUT_LMAP  44236800                    // B*20*M2   =  4,608,000
#define OUT_GMAP  48844800                    // B*20*960² = 73,728,000
#define OUT_LP    122572800                   // B*T*3
#define OUT_GP    122572896                   // B*T*3
#define OUT_BNDS  122572992                   // B*T*4 (written as float)
#define OUT_ORGS  122573120                   // B*T*3

// workspace layout (float element offsets into d_ws)
#define WS_LPOSE   0                          // T*B*3 = 96
#define WS_ANYDONE 96                         // B (float 0/1), padded to 128
#define WS_SCR     128                        // Tn * STEP_FLOATS
#define STEP_FLOATS ((size_t)Bn * M2n * 18)   // exp(B*M2) + obst(B*M2) + sem(B*16*M2)

// ---------------- kernels ----------------

// Poses/bounds/origins evolve independently of the maps: compute all T steps
// up front, write pose outputs, stash per-step lpose + any_done flag in ws.
__global__ void pose_kernel(const float* __restrict__ pose_delta,
                            const int* __restrict__ done_flags,
                            const int* __restrict__ upd_flags,
                            const float* __restrict__ init_lpose,
                            const float* __restrict__ init_gpose,
                            const int* __restrict__ init_bounds,
                            const float* __restrict__ init_origins,
                            float* __restrict__ ws_lpose,
                            float* __restrict__ ws_anydone,
                            float* __restrict__ out_lp,
                            float* __restrict__ out_gp,
                            float* __restrict__ out_bnds,
                            float* __restrict__ out_orgs) {
#pragma clang fp contract(off)
    int b = threadIdx.x;
    if (b >= Bn) return;
    float lx = init_lpose[b * 3 + 0], ly = init_lpose[b * 3 + 1], lz = init_lpose[b * 3 + 2];
    float gx = init_gpose[b * 3 + 0], gy = init_gpose[b * 3 + 1], gz = init_gpose[b * 3 + 2];
    int b0 = init_bounds[b * 4 + 0], b1 = init_bounds[b * 4 + 1];
    int b2i = init_bounds[b * 4 + 2], b3 = init_bounds[b * 4 + 3];
    float ox = init_origins[b * 3 + 0], oy = init_origins[b * 3 + 1], oz = init_origins[b * 3 + 2];
    float anyd = 0.0f;
    for (int t = 0; t < Tn; t++) {
        int done = done_flags[b * Tn + t];
        int upd  = upd_flags[b * Tn + t];
        if (done) {
            lx = 600.0f; ly = 600.0f; lz = 0.0f;
            gx = 2400.0f; gy = 2400.0f; gz = 0.0f;
            b0 = 360; b1 = 600; b2i = 360; b3 = 600;
            ox = 1800.0f; oy = 1800.0f; oz = 0.0f;
            anyd = 1.0f;
        }
        float th = lz * DEG2RADf;
        float c = cosf(th), s = sinf(th);
        float d0 = pose_delta[(b * Tn + t) * 3 + 0];
        float d1 = pose_delta[(b * Tn + t) * 3 + 1];
        float d2 = pose_delta[(b * Tn + t) * 3 + 2];
        lx = lx + (d0 * c - d1 * s);
        ly = ly + (d0 * s + d1 * c);
        lz = lz + d2;
        if (upd) { gx = lx + ox; gy = ly + oy; gz = lz + oz; }
        ws_lpose[(t * Bn + b) * 3 + 0] = lx;
        ws_lpose[(t * Bn + b) * 3 + 1] = ly;
        ws_lpose[(t * Bn + b) * 3 + 2] = lz;
        out_lp[(b * Tn + t) * 3 + 0] = lx;
        out_lp[(b * Tn + t) * 3 + 1] = ly;
        out_lp[(b * Tn + t) * 3 + 2] = lz;
        out_gp[(b * Tn + t) * 3 + 0] = gx;
        out_gp[(b * Tn + t) * 3 + 1] = gy;
        out_gp[(b * Tn + t) * 3 + 2] = gz;
        out_bnds[(b * Tn + t) * 4 + 0] = (float)b0;
        out_bnds[(b * Tn + t) * 4 + 1] = (float)b1;
        out_bnds[(b * Tn + t) * 4 + 2] = (float)b2i;
        out_bnds[(b * Tn + t) * 4 + 3] = (float)b3;
        out_orgs[(b * Tn + t) * 3 + 0] = ox;
        out_orgs[(b * Tn + t) * 3 + 1] = oy;
        out_orgs[(b * Tn + t) * 3 + 2] = oz;
    }
    ws_anydone[b] = anyd;
}

// All (t,b,pixel) in one launch: unproject, transform, splat into per-t scratch.
// exp/obst are used downstream only as clip(count,0,1) -> plain stores of 1.0f
// (all racers store the same value). Only 16 sem channels need atomicAdd.
__global__ void project_kernel(const float* __restrict__ obs,
                               const float* __restrict__ cam,
                               const float* __restrict__ ws_lpose,
                               float* __restrict__ scr,
                               float fx) {
#pragma clang fp contract(off)
    int idx = blockIdx.x * blockDim.x + threadIdx.x;
    if (idx >= Tn * Bn * HWn) return;
    int p = idx % HWn;
    int tb = idx / HWn;
    int b = tb % Bn;
    int t = tb / Bn;
    int h = p / Wn, w = p % Wn;
    const float* ob = obs + (size_t)((b * Tn + t) * MAP_CHn) * HWn;
    float depth = ob[3 * HWn + p] * 400.0f + 50.0f;
    float u = (float)w - 80.0f;   // CX = W/2
    float v = 60.0f - (float)h;   // CY = H/2
    float px = u * depth / fx;
    float py = v * depth / fx;    // FY == FX
    float pz = depth;
    const float* Tm = cam + (size_t)(b * Tn + t) * 16;
    float X = ((Tm[0] * px + Tm[1] * py) + Tm[2] * pz) + Tm[3];
    float Y = ((Tm[4] * px + Tm[5] * py) + Tm[6] * pz) + Tm[7];
    float Z = ((Tm[8] * px + Tm[9] * py) + Tm[10] * pz) + Tm[11];
    float x_f = Z;
    float y_l = -X;
    float z_u = Y + 88.0f;        // CAM_H_CM
    float lx = ws_lpose[(t * Bn + b) * 3 + 0];
    float ly = ws_lpose[(t * Bn + b) * 3 + 1];
    float lz = ws_lpose[(t * Bn + b) * 3 + 2];
    float th2 = lz * DEG2RADf;
    float c2 = cosf(th2), s2 = sinf(th2);
    float wx = (lx + x_f * c2) - y_l * s2;
    float wy = (ly + x_f * s2) + y_l * c2;
    int ix = (int)floorf(wx / 5.0f);
    int iy = (int)floorf(wy / 5.0f);
    bool valid = (depth > 25.0f) && (depth < 500.0f) &&
                 (ix >= 0) && (ix < LOCAL_Mn) && (iy >= 0) && (iy < LOCAL_Mn);
    if (!valid) return;
    int flat = iy * LOCAL_Mn + ix;
    float* sc = scr + (size_t)t * STEP_FLOATS;
    sc[b * M2n + flat] = 1.0f;                                   // exp hit
    if (z_u > 25.0f && z_u < 150.0f)
        sc[Bn * M2n + b * M2n + flat] = 1.0f;                    // obst hit
    float* sem = sc + 2 * Bn * M2n;
#pragma unroll
    for (int c = 0; c < CATn; c++) {
        float sv = ob[(size_t)(NON_SEMn + c) * HWn + p];
        atomicAdd(&sem[(size_t)(b * CATn + c) * M2n + flat], sv);
    }
}

// Per cell: carry lmap(20) + crop(20) in registers across all T steps.
// Reads 18 scratch ch/step, writes 24 feat ch/step; final lmap + gmap window.
__global__ void update_kernel(const float* __restrict__ scr,
                              const int* __restrict__ done_flags,
                              const int* __restrict__ upd_flags,
                              const float* __restrict__ ws_lpose,
                              const float* __restrict__ init_lmap,
                              const float* __restrict__ init_gmap,
                              const int* __restrict__ init_bounds,
                              float* __restrict__ out_feats,
                              float* __restrict__ out_lmap,
                              float* __restrict__ out_gmap) {
#pragma clang fp contract(off)
    int idx = blockIdx.x * blockDim.x + threadIdx.x;
    if (idx >= Bn * M2n) return;
    int b = idx / M2n, j = idx % M2n;
    int y = j / LOCAL_Mn, x = j % LOCAL_Mn;
    int y1 = init_bounds[b * 4 + 0];
    int x1 = init_bounds[b * 4 + 2];

    float lm[MAP_CHn], cr[MAP_CHn];
#pragma unroll
    for (int ch = 0; ch < MAP_CHn; ch++)
        lm[ch] = init_lmap[((size_t)(b * MAP_CHn + ch)) * M2n + j];
#pragma unroll
    for (int ch = 0; ch < MAP_CHn; ch++)
        cr[ch] = init_gmap[((size_t)(b * MAP_CHn + ch) * GLOBAL_Mn + (y1 + y)) * GLOBAL_Mn + (x1 + x)];

    for (int t = 0; t < Tn; t++) {
        int done = done_flags[b * Tn + t];
        int upd  = upd_flags[b * Tn + t];
        if (done) {
#pragma unroll
            for (int ch = 0; ch < MAP_CHn; ch++) { lm[ch] = 0.0f; cr[ch] = 0.0f; }
        }
        float lx = ws_lpose[(t * Bn + b) * 3 + 0];
        float ly = ws_lpose[(t * Bn + b) * 3 + 1];
        float dxg = (float)x - lx / 5.0f;
        float dyg = (float)y - ly / 5.0f;
        float d2 = dxg * dxg + dyg * dyg;
        float agent = (d2 <= 4.0f) ? 1.0f : 0.0f;
        float close = (d2 <= 9.0f) ? 1.0f : 0.0f;

        const float* sc = scr + (size_t)t * STEP_FLOATS;
        float expv  = sc[b * M2n + j];
        float obstv = sc[Bn * M2n + b * M2n + j];
        lm[0] = fmaxf(lm[0], fminf(fmaxf(obstv, 0.0f), 1.0f));
        lm[1] = fmaxf(lm[1], fminf(fmaxf(expv, 0.0f), 1.0f));
        lm[2] = agent;
        lm[3] = fmaxf(lm[3], close);
        const float* sem = sc + 2 * Bn * M2n;
#pragma unroll
        for (int c = 0; c < CATn; c++) {
            float sv = sem[((size_t)(b * CATn + c)) * M2n + j];
            lm[NON_SEMn + c] = fmaxf(lm[NON_SEMn + c], fminf(fmaxf(sv, 0.0f), 1.0f));
        }
        if (upd) {
#pragma unroll
            for (int ch = 0; ch < MAP_CHn; ch++) cr[ch] = fmaxf(cr[ch], lm[ch]);
        }

        size_t fb = ((size_t)(b * Tn + t) * FEAT_CHn) * M2n + j;
#pragma unroll
        for (int ch = 0; ch < NON_SEMn; ch++) out_feats[fb + (size_t)ch * M2n] = lm[ch];
#pragma unroll
        for (int ch = 0; ch < NON_SEMn; ch++) out_feats[fb + (size_t)(NON_SEMn + ch) * M2n] = cr[ch];
#pragma unroll
        for (int c = 0; c < CATn; c++) out_feats[fb + (size_t)(2 * NON_SEMn + c) * M2n] = lm[NON_SEMn + c];
    }

#pragma unroll
    for (int ch = 0; ch < MAP_CHn; ch++)
        out_lmap[((size_t)(b * MAP_CHn + ch)) * M2n + j] = lm[ch];
#pragma unroll
    for (int ch = 0; ch < MAP_CHn; ch++)
        out_gmap[((size_t)(b * MAP_CHn + ch) * GLOBAL_Mn + (y1 + y)) * GLOBAL_Mn + (x1 + x)] = cr[ch];
}

// Outside-window global map, float4-vectorized. Window cells are written by
// update_kernel; the fixed window [360,600) is 4-aligned so float4 never
// straddles its boundary. anydone -> write zeros without reading init_gmap.
__global__ void final_gmap_kernel(const float* __restrict__ init_gmap,
                                  const int* __restrict__ init_bounds,
                                  const float* __restrict__ anydone,
                                  float* __restrict__ out_gmap) {
    size_t i4 = (size_t)blockIdx.x * blockDim.x + threadIdx.x;
    const size_t total4 = (size_t)Bn * MAP_CHn * GLOBAL_Mn * GLOBAL_Mn / 4;
    if (i4 >= total4) return;
    size_t f = i4 * 4;
    int gx = (int)(f % GLOBAL_Mn);
    size_t r = f / GLOBAL_Mn;
    int gy = (int)(r % GLOBAL_Mn);
    size_t bc = r / GLOBAL_Mn;      // b*MAP_CH + ch
    int b = (int)(bc / MAP_CHn);
    int y1 = init_bounds[b * 4 + 0];
    int x1 = init_bounds[b * 4 + 2];
    if (gy >= y1 && gy < y1 + LOCAL_Mn && gx >= x1 && gx < x1 + LOCAL_Mn) return;
    float4 v;
    if (anydone[b] != 0.0f) {
        v = make_float4(0.0f, 0.0f, 0.0f, 0.0f);
    } else {
        v = *(const float4*)(init_gmap + f);
    }
    *(float4*)(out_gmap + f) = v;
}

// ---------------- launch ----------------
extern "C" void kernel_launch(void* const* d_in, const int* in_sizes, int n_in,
                              void* d_out, int out_size, void* d_ws, size_t ws_size,
                              hipStream_t stream) {
    const float* obs        = (const float*)d_in[0];
    const float* pose_delta = (const float*)d_in[1];
    const int*   done_flags = (const int*)d_in[2];
    const int*   upd_flags  = (const int*)d_in[3];
    const float* cam_poses  = (const float*)d_in[4];
    const float* init_lmap  = (const float*)d_in[5];
    const float* init_gmap  = (const float*)d_in[6];
    const float* init_lpose = (const float*)d_in[7];
    const float* init_gpose = (const float*)d_in[8];
    const int*   init_bnds  = (const int*)d_in[9];
    const float* init_orgs  = (const float*)d_in[10];

    float* out = (float*)d_out;
    float* ws  = (float*)d_ws;

    float* ws_lpose = ws + WS_LPOSE;
    float* ws_anyd  = ws + WS_ANYDONE;
    float* scr      = ws + WS_SCR;

    // FX = W / (2*tan(deg2rad(HFOV)/2)), double math then f32 (matches numpy)
    float fx = (float)(160.0 / (2.0 * tan(79.0 * M_PI / 180.0 / 2.0)));

    pose_kernel<<<1, 64, 0, stream>>>(pose_delta, done_flags, upd_flags,
                                      init_lpose, init_gpose, init_bnds, init_orgs,
                                      ws_lpose, ws_anyd,
                                      out + OUT_LP, out + OUT_GP,
                                      out + OUT_BNDS, out + OUT_ORGS);

    hipMemsetAsync(scr, 0, (size_t)Tn * STEP_FLOATS * sizeof(float), stream);

    project_kernel<<<(Tn * Bn * HWn + 255) / 256, 256, 0, stream>>>(
        obs, cam_poses, ws_lpose, scr, fx);

    update_kernel<<<(Bn * M2n + 255) / 256, 256, 0, stream>>>(
        scr, done_flags, upd_flags, ws_lpose, init_lmap, init_gmap, init_bnds,
        out + OUT_FEATS, out + OUT_LMAP, out + OUT_GMAP);

    const size_t gmap_total4 = (size_t)Bn * MAP_CHn * GLOBAL_Mn * GLOBAL_Mn / 4;
    final_gmap_kernel<<<(int)((gmap_total4 + 255) / 256), 256, 0, stream>>>(
        init_gmap, init_bnds, ws_anyd, out + OUT_GMAP);
}